// Round 8
// baseline (264.446 us; speedup 1.0000x reference)
//
#include <hip/hip_runtime.h>
#include <hip/hip_bf16.h>

// Problem constants
#define NN 50000      // nodes
#define NE 800000     // edges
#define FD 4          // features
#define TD 12         // timesteps
#define CD 32         // channels
#define HD 12         // horizon
#define FT 48         // FD*TD
#define NBANK 8       // chain banks per node (contention reduction)

// Workspace layout (4-byte element offsets)
#define OFF_HEAD   0                    // int[NBANK*NN] chain heads
#define OFF_NEXT   400000               // int[NE]       chain next pointers
#define OFF_DIS    1200000              // float[NN]
#define OFF_Y      1250000              // float[NN*FT]
#define OFF_CST    3650000              // float[512]
// cst block: Az[128] @0, cz[32] @128, Ah[128] @160, ch[32] @288, probs[12] @320

// ---------------------------------------------------------------------------
// init: head = -1 everywhere; last block computes the fused tiny matrices.
// (H0 stays zero in the reference => R-gate dead; only top 32 rows of Wl*
//  matter:  Az = Wz@Wlz[0:32,:],  cz = blz + bz@Wlz[0:32,:],  same for h.)
// ---------------------------------------------------------------------------
#define INIT_BLKS ((NBANK * NN + 255) / 256)   // 1563
__global__ void init_pre_kernel(int* __restrict__ head,
                                const float* __restrict__ Wz, const float* __restrict__ bz,
                                const float* __restrict__ Wlz, const float* __restrict__ blz,
                                const float* __restrict__ Wh, const float* __restrict__ bh,
                                const float* __restrict__ Wlh, const float* __restrict__ blh,
                                const float* __restrict__ attention,
                                float* __restrict__ cst) {
    int tid = threadIdx.x;
    if (blockIdx.x < INIT_BLKS) {
        int i = blockIdx.x * 256 + tid;
        if (i < NBANK * NN) head[i] = -1;
        return;
    }
    // one extra block: precompute
    if (tid < 128) {
        int f = tid >> 5, c = tid & 31;
        float s = 0.f, s2 = 0.f;
        #pragma unroll
        for (int k = 0; k < 32; ++k) {
            s  += Wz[f*32 + k] * Wlz[k*32 + c];
            s2 += Wh[f*32 + k] * Wlh[k*32 + c];
        }
        cst[tid]       = s;   // Az
        cst[160 + tid] = s2;  // Ah
    } else if (tid < 160) {
        int c = tid - 128;
        float s = blz[c], s2 = blh[c];
        #pragma unroll
        for (int k = 0; k < 32; ++k) {
            s  += bz[k] * Wlz[k*32 + c];
            s2 += bh[k] * Wlh[k*32 + c];
        }
        cst[128 + c] = s;   // cz
        cst[288 + c] = s2;  // ch
    } else if (tid == 160) {
        float m = -1e30f;
        for (int t = 0; t < TD; ++t) m = fmaxf(m, attention[t]);
        float e[TD], s = 0.f;
        #pragma unroll
        for (int t = 0; t < TD; ++t) { e[t] = __expf(attention[t] - m); s += e[t]; }
        float inv = 1.f / s;
        #pragma unroll
        for (int t = 0; t < TD; ++t) cst[320 + t] = e[t] * inv;
    }
}

// build per-node banked linked lists: 1 banked atomicExch + 1 coalesced write
__global__ void build_kernel(const int* __restrict__ ei, int* __restrict__ head,
                             int* __restrict__ next) {
    int e = blockIdx.x * blockDim.x + threadIdx.x;
    if (e < NE) {
        int c = ei[NE + e];
        int old = atomicExch(&head[(e & (NBANK-1)) * NN + c], e);
        next[e] = old;
    }
}

// weighted in-degree by chain walk (contention-free) -> dis
__global__ void degdis_kernel(const int* __restrict__ head, const int* __restrict__ next,
                              const float* __restrict__ w, float* __restrict__ dis) {
    int i = blockIdx.x * blockDim.x + threadIdx.x;
    if (i < NN) {
        float s = 0.f;
        #pragma unroll
        for (int b = 0; b < NBANK; ++b) {
            int e = head[b * NN + i];
            while (e >= 0) { s += w[e]; e = next[e]; }
        }
        dis[i] = rsqrtf(s + 1.0f);
    }
}

// gather: thread = (node, float4-chunk); walks the node's 8 chains; zero atomics.
// y[i,:] = dis[i]^2 * x[i,:] + dis[i] * sum_e dis[row]*w * x[row,:]
__global__ __launch_bounds__(256) void gather_kernel(const float4* __restrict__ x4,
                                                     const float* __restrict__ dis,
                                                     const int* __restrict__ head,
                                                     const int* __restrict__ next,
                                                     const int* __restrict__ ei,
                                                     const float* __restrict__ w,
                                                     float4* __restrict__ y4) {
    int j = blockIdx.x * blockDim.x + threadIdx.x;
    if (j >= NN * (FT/4)) return;
    int i  = j / (FT/4);
    int ch = j - i * (FT/4);
    float d = dis[i];
    float4 a = x4[i * (FT/4) + ch];
    float4 acc = make_float4(0.f, 0.f, 0.f, 0.f);
    #pragma unroll
    for (int b = 0; b < NBANK; ++b) {
        int e = head[b * NN + i];
        while (e >= 0) {
            int r = ei[e];
            float nv = dis[r] * w[e];
            float4 v = x4[r * (FT/4) + ch];
            acc.x += nv * v.x; acc.y += nv * v.y; acc.z += nv * v.z; acc.w += nv * v.w;
            e = next[e];
        }
    }
    float s0 = d * d;
    y4[j] = make_float4(a.x*s0 + d*acc.x, a.y*s0 + d*acc.y,
                        a.z*s0 + d*acc.z, a.w*s0 + d*acc.w);
}

// Per-node folded GRU: Z=sig(y_t@Az+cz), Ht=tanh(y_t@Ah+ch),
// Hacc += p[t]*(1-Z)*Ht ; out = relu(Hacc)@Wout + bout
__global__ __launch_bounds__(256) void gru_kernel(const float* __restrict__ y,
                                                  const float* __restrict__ cst,
                                                  const float* __restrict__ Wout,
                                                  const float* __restrict__ bout,
                                                  float* __restrict__ out) {
    __shared__ float sAz[128], sAh[128], sCz[32], sCh[32], sP[TD];
    __shared__ float sWout[CD * HD], sBout[HD];
    __shared__ float sy[8][FT];
    __shared__ float hbuf[8][CD];

    int tid = threadIdx.x;
    if (tid < 128) { sAz[tid] = cst[tid]; sAh[tid] = cst[160 + tid]; }
    if (tid < 32)  { sCz[tid] = cst[128 + tid]; sCh[tid] = cst[288 + tid]; }
    if (tid < TD)  { sP[tid] = cst[320 + tid]; sBout[tid] = bout[tid]; }
    for (int k = tid; k < CD * HD; k += 256) sWout[k] = Wout[k];

    int b0 = blockIdx.x * 8;
    float* syf = &sy[0][0];
    for (int k = tid; k < 8 * FT; k += 256) {
        int idx = b0 * FT + k;
        syf[k] = (idx < NN * FT) ? y[idx] : 0.f;
    }
    __syncthreads();

    int ln = tid >> 5;
    int c  = tid & 31;

    float az0 = sAz[c], az1 = sAz[32 + c], az2 = sAz[64 + c], az3 = sAz[96 + c];
    float ah0 = sAh[c], ah1 = sAh[32 + c], ah2 = sAh[64 + c], ah3 = sAh[96 + c];
    float czc = sCz[c], chc = sCh[c];

    float hacc = 0.f;
    #pragma unroll
    for (int t = 0; t < TD; ++t) {
        float y0 = sy[ln][0*TD + t];
        float y1 = sy[ln][1*TD + t];
        float y2 = sy[ln][2*TD + t];
        float y3 = sy[ln][3*TD + t];
        float z = czc + y0*az0 + y1*az1 + y2*az2 + y3*az3;
        float h = chc + y0*ah0 + y1*ah1 + y2*ah2 + y3*ah3;
        float Z  = 1.f / (1.f + __expf(-z));
        float e2 = __expf(2.f * h);
        float Ht = (e2 - 1.f) / (e2 + 1.f);
        hacc += sP[t] * (1.f - Z) * Ht;
    }

    hbuf[ln][c] = fmaxf(hacc, 0.f);
    __syncthreads();

    if (tid < 8 * HD) {
        int lnode = tid / HD, hor = tid - lnode * HD;
        int gn = b0 + lnode;
        if (gn < NN) {
            float s = sBout[hor];
            #pragma unroll
            for (int k = 0; k < CD; ++k) s += hbuf[lnode][k] * sWout[k * HD + hor];
            out[gn * HD + hor] = s;
        }
    }
}

extern "C" void kernel_launch(void* const* d_in, const int* in_sizes, int n_in,
                              void* d_out, int out_size, void* d_ws, size_t ws_size,
                              hipStream_t stream) {
    const float* x      = (const float*)d_in[0];
    const int*   ei     = (const int*)d_in[1];    // int32, layout [rows..., cols...]
    const float* ew     = (const float*)d_in[2];
    const float* attn   = (const float*)d_in[3];
    const float* Wz     = (const float*)d_in[4];
    const float* bz     = (const float*)d_in[5];
    const float* Wlz    = (const float*)d_in[6];
    const float* blz    = (const float*)d_in[7];
    // d_in[8..11] = Wr, br, Wlr, blr — dead (H0 == 0 forever)
    const float* Wh     = (const float*)d_in[12];
    const float* bh     = (const float*)d_in[13];
    const float* Wlh    = (const float*)d_in[14];
    const float* blh    = (const float*)d_in[15];
    const float* Wout   = (const float*)d_in[16];
    const float* bout   = (const float*)d_in[17];
    float* out = (float*)d_out;

    float* ws   = (float*)d_ws;
    int*   head = (int*)(ws + OFF_HEAD);
    int*   next = (int*)(ws + OFF_NEXT);
    float* dis  = ws + OFF_DIS;
    float* y    = ws + OFF_Y;
    float* cst  = ws + OFF_CST;

    init_pre_kernel<<<INIT_BLKS + 1, 256, 0, stream>>>(head, Wz, bz, Wlz, blz,
                                                       Wh, bh, Wlh, blh, attn, cst);

    build_kernel<<<(NE + 255) / 256, 256, 0, stream>>>(ei, head, next);

    degdis_kernel<<<(NN + 255) / 256, 256, 0, stream>>>(head, next, ew, dis);

    gather_kernel<<<(NN * (FT/4) + 255) / 256, 256, 0, stream>>>(
        (const float4*)x, dis, head, next, ei, ew, (float4*)y);

    gru_kernel<<<(NN + 7) / 8, 256, 0, stream>>>(y, cst, Wout, bout, out);
}

// Round 10
// 234.518 us; speedup vs baseline: 1.1276x; 1.1276x over previous
//
#include <hip/hip_runtime.h>
#include <hip/hip_bf16.h>

// Problem constants
#define NN 50000      // nodes
#define NE 800000     // edges
#define FD 4          // features
#define TD 12         // timesteps
#define CD 32         // channels
#define HD 12         // horizon
#define FT 48         // FD*TD
#define NBANK 8       // chain banks per node

// Workspace layout (4-byte element offsets)
#define OFF_HEAD   0                    // int[NBANK*NN] chain heads
#define OFF_NEXT   400000               // int[NE]       chain next pointers
#define OFF_DIS    1200000              // float[NN]
#define OFF_CST    1250000              // float[512]
// cst block: Az[128] @0, cz[32] @128, Ah[128] @160, ch[32] @288, probs[12] @320

// ---------------------------------------------------------------------------
// init: head = -1 everywhere; one extra block computes the fused tiny matrices.
// (H0 stays zero in the reference => R-gate dead; only top 32 rows of Wl*
//  matter:  Az = Wz@Wlz[0:32,:],  cz = blz + bz@Wlz[0:32,:],  same for h.)
// ---------------------------------------------------------------------------
#define INIT_BLKS ((NBANK * NN + 255) / 256)   // 1563
__global__ void init_pre_kernel(int* __restrict__ head,
                                const float* __restrict__ Wz, const float* __restrict__ bz,
                                const float* __restrict__ Wlz, const float* __restrict__ blz,
                                const float* __restrict__ Wh, const float* __restrict__ bh,
                                const float* __restrict__ Wlh, const float* __restrict__ blh,
                                const float* __restrict__ attention,
                                float* __restrict__ cst) {
    int tid = threadIdx.x;
    if (blockIdx.x < INIT_BLKS) {
        int i = blockIdx.x * 256 + tid;
        if (i < NBANK * NN) head[i] = -1;
        return;
    }
    if (tid < 128) {
        int f = tid >> 5, c = tid & 31;
        float s = 0.f, s2 = 0.f;
        #pragma unroll
        for (int k = 0; k < 32; ++k) {
            s  += Wz[f*32 + k] * Wlz[k*32 + c];
            s2 += Wh[f*32 + k] * Wlh[k*32 + c];
        }
        cst[tid]       = s;   // Az
        cst[160 + tid] = s2;  // Ah
    } else if (tid < 160) {
        int c = tid - 128;
        float s = blz[c], s2 = blh[c];
        #pragma unroll
        for (int k = 0; k < 32; ++k) {
            s  += bz[k] * Wlz[k*32 + c];
            s2 += bh[k] * Wlh[k*32 + c];
        }
        cst[128 + c] = s;   // cz
        cst[288 + c] = s2;  // ch
    } else if (tid == 160) {
        float m = -1e30f;
        for (int t = 0; t < TD; ++t) m = fmaxf(m, attention[t]);
        float e[TD], s = 0.f;
        #pragma unroll
        for (int t = 0; t < TD; ++t) { e[t] = __expf(attention[t] - m); s += e[t]; }
        float inv = 1.f / s;
        #pragma unroll
        for (int t = 0; t < TD; ++t) cst[320 + t] = e[t] * inv;
    }
}

// build per-node banked linked lists: 1 banked atomicExch + 1 coalesced write
__global__ void build_kernel(const int* __restrict__ ei, int* __restrict__ head,
                             int* __restrict__ next) {
    int e = blockIdx.x * blockDim.x + threadIdx.x;
    if (e < NE) {
        int c = ei[NE + e];
        int old = atomicExch(&head[(e & (NBANK-1)) * NN + c], e);
        next[e] = old;
    }
}

// weighted in-degree: 8 lanes per node, one bank chain each (dep-depth ~2),
// then shfl-xor reduce within the 8-lane segment.
__global__ void degdis_kernel(const int* __restrict__ head, const int* __restrict__ next,
                              const float* __restrict__ w, float* __restrict__ dis) {
    int t = blockIdx.x * blockDim.x + threadIdx.x;   // NN*8 threads
    int i = t >> 3;
    int b = t & 7;
    if (i >= NN) return;
    float s = 0.f;
    int e = head[b * NN + i];
    while (e >= 0) { s += w[e]; e = next[e]; }
    s += __shfl_xor(s, 1, 8);
    s += __shfl_xor(s, 2, 8);
    s += __shfl_xor(s, 4, 8);
    if (b == 0) dis[i] = rsqrtf(s + 1.0f);
}

// ---------------------------------------------------------------------------
// Fused gather + GRU + output. 16 lanes per node (4 nodes/wave, 16 nodes/block).
// Phase A: lanes 0..7 walk bank chains, broadcast (row, norm) via __shfl;
//          lanes 0..11 accumulate their float4 chunk of y. Metadata read ONCE
//          per edge (was x12 in round 8 -> 217MB FETCH).
// Phase B: y staged in LDS; 16 lanes/node compute 2 GRU channels each.
// Phase C: 16 nodes x 12 horizons output matvec.
// ---------------------------------------------------------------------------
__global__ __launch_bounds__(256) void gather_gru_kernel(
        const float4* __restrict__ x4, const float* __restrict__ dis,
        const int* __restrict__ head, const int* __restrict__ next,
        const int* __restrict__ ei, const float* __restrict__ w,
        const float* __restrict__ cst, const float* __restrict__ Wout,
        const float* __restrict__ bout, float* __restrict__ out) {
    __shared__ float sy[16][FT];         // 16 nodes' y
    __shared__ float hbuf[16][CD];
    __shared__ float sAz[128], sAh[128], sCz[32], sCh[32], sP[TD];
    __shared__ float sWout[CD * HD], sBout[HD];

    int tid = threadIdx.x;
    if (tid < 128) { sAz[tid] = cst[tid]; sAh[tid] = cst[160 + tid]; }
    if (tid < 32)  { sCz[tid] = cst[128 + tid]; sCh[tid] = cst[288 + tid]; }
    if (tid < TD)  { sP[tid] = cst[320 + tid]; sBout[tid] = bout[tid]; }
    for (int k = tid; k < CD * HD; k += 256) sWout[k] = Wout[k];

    int lane = tid & 63;
    int g    = tid & 15;          // lane within node group
    int ln   = tid >> 4;          // local node 0..15
    int i    = blockIdx.x * 16 + ln;   // NN*16 == grid threads exactly

    // ---- Phase A: chain walk + gather ----
    float d = dis[i];
    int e = (g < 8) ? head[g * NN + i] : -1;
    float4 acc = make_float4(0.f, 0.f, 0.f, 0.f);

    unsigned long long bal = __ballot(e >= 0);
    unsigned int act = (unsigned int)((bal >> (lane & 48)) & 0xFFFFu);
    while (act) {
        int r = -1; float nv = 0.f; int nxt = -1;
        if (e >= 0) {
            r   = ei[e];
            nv  = dis[r] * w[e];
            nxt = next[e];
        }
        #pragma unroll
        for (int b = 0; b < NBANK; ++b) {
            int src  = (lane & 48) + b;
            int rb   = __shfl(r, src, 64);
            float nb = __shfl(nv, src, 64);
            if (rb >= 0 && g < 12) {
                float4 v = x4[rb * (FT/4) + g];
                acc.x += nb * v.x; acc.y += nb * v.y;
                acc.z += nb * v.z; acc.w += nb * v.w;
            }
        }
        e = nxt;
        bal = __ballot(e >= 0);
        act = (unsigned int)((bal >> (lane & 48)) & 0xFFFFu);
    }

    if (g < 12) {
        float4 a = x4[i * (FT/4) + g];
        float s0 = d * d;
        sy[ln][g*4 + 0] = a.x * s0 + d * acc.x;
        sy[ln][g*4 + 1] = a.y * s0 + d * acc.y;
        sy[ln][g*4 + 2] = a.z * s0 + d * acc.z;
        sy[ln][g*4 + 3] = a.w * s0 + d * acc.w;
    }
    __syncthreads();

    // ---- Phase B: GRU, 2 channels per lane (c0=g, c1=g+16) ----
    {
        int c0 = g, c1 = g + 16;
        float az00 = sAz[c0], az01 = sAz[32+c0], az02 = sAz[64+c0], az03 = sAz[96+c0];
        float az10 = sAz[c1], az11 = sAz[32+c1], az12 = sAz[64+c1], az13 = sAz[96+c1];
        float ah00 = sAh[c0], ah01 = sAh[32+c0], ah02 = sAh[64+c0], ah03 = sAh[96+c0];
        float ah10 = sAh[c1], ah11 = sAh[32+c1], ah12 = sAh[64+c1], ah13 = sAh[96+c1];
        float cz0 = sCz[c0], cz1 = sCz[c1], ch0 = sCh[c0], ch1 = sCh[c1];

        float hacc0 = 0.f, hacc1 = 0.f;
        #pragma unroll
        for (int t = 0; t < TD; ++t) {
            float y0 = sy[ln][0*TD + t];
            float y1 = sy[ln][1*TD + t];
            float y2 = sy[ln][2*TD + t];
            float y3 = sy[ln][3*TD + t];
            float z0 = cz0 + y0*az00 + y1*az01 + y2*az02 + y3*az03;
            float z1 = cz1 + y0*az10 + y1*az11 + y2*az12 + y3*az13;
            float h0 = ch0 + y0*ah00 + y1*ah01 + y2*ah02 + y3*ah03;
            float h1 = ch1 + y0*ah10 + y1*ah11 + y2*ah12 + y3*ah13;
            float Z0 = 1.f / (1.f + __expf(-z0));
            float Z1 = 1.f / (1.f + __expf(-z1));
            float e0 = __expf(2.f * h0);
            float e1 = __expf(2.f * h1);
            float H0v = (e0 - 1.f) / (e0 + 1.f);
            float H1v = (e1 - 1.f) / (e1 + 1.f);
            float p = sP[t];
            hacc0 += p * (1.f - Z0) * H0v;
            hacc1 += p * (1.f - Z1) * H1v;
        }
        hbuf[ln][c0] = fmaxf(hacc0, 0.f);
        hbuf[ln][c1] = fmaxf(hacc1, 0.f);
    }
    __syncthreads();

    // ---- Phase C: out = relu(Hacc) @ Wout + bout ----
    if (tid < 16 * HD) {
        int lnode = tid / HD, hor = tid - lnode * HD;
        int gn = blockIdx.x * 16 + lnode;
        float s = sBout[hor];
        #pragma unroll
        for (int k = 0; k < CD; ++k) s += hbuf[lnode][k] * sWout[k * HD + hor];
        out[gn * HD + hor] = s;
    }
}

extern "C" void kernel_launch(void* const* d_in, const int* in_sizes, int n_in,
                              void* d_out, int out_size, void* d_ws, size_t ws_size,
                              hipStream_t stream) {
    const float* x      = (const float*)d_in[0];
    const int*   ei     = (const int*)d_in[1];    // int32, layout [rows..., cols...]
    const float* ew     = (const float*)d_in[2];
    const float* attn   = (const float*)d_in[3];
    const float* Wz     = (const float*)d_in[4];
    const float* bz     = (const float*)d_in[5];
    const float* Wlz    = (const float*)d_in[6];
    const float* blz    = (const float*)d_in[7];
    // d_in[8..11] = Wr, br, Wlr, blr — dead (H0 == 0 forever)
    const float* Wh     = (const float*)d_in[12];
    const float* bh     = (const float*)d_in[13];
    const float* Wlh    = (const float*)d_in[14];
    const float* blh    = (const float*)d_in[15];
    const float* Wout   = (const float*)d_in[16];
    const float* bout   = (const float*)d_in[17];
    float* out = (float*)d_out;

    float* ws   = (float*)d_ws;
    int*   head = (int*)(ws + OFF_HEAD);
    int*   next = (int*)(ws + OFF_NEXT);
    float* dis  = ws + OFF_DIS;
    float* cst  = ws + OFF_CST;

    init_pre_kernel<<<INIT_BLKS + 1, 256, 0, stream>>>(head, Wz, bz, Wlz, blz,
                                                       Wh, bh, Wlh, blh, attn, cst);

    build_kernel<<<(NE + 255) / 256, 256, 0, stream>>>(ei, head, next);

    degdis_kernel<<<(NN * 8 + 255) / 256, 256, 0, stream>>>(head, next, ew, dis);

    gather_gru_kernel<<<NN / 16, 256, 0, stream>>>(
        (const float4*)x, dis, head, next, ei, ew, cst, Wout, bout, out);
}

// Round 11
// 212.774 us; speedup vs baseline: 1.2428x; 1.1022x over previous
//
#include <hip/hip_runtime.h>
#include <hip/hip_bf16.h>

// Problem constants
#define NN 50000      // nodes
#define NE 800000     // edges
#define FD 4          // features
#define TD 12         // timesteps
#define CD 32         // channels
#define HD 12         // horizon
#define FT 48         // FD*TD
#define NBANK 8       // chain banks per node

// Workspace layout (4-byte element offsets)
#define OFF_HEAD   0                    // int[NBANK*NN] chain heads
#define OFF_NEXT   400000               // int[NE]       chain next pointers
#define OFF_DIS    1200000              // float[NN]
#define OFF_CST    1250000              // float[512]
// cst block: Az[128] @0, cz[32] @128, Ah[128] @160, ch[32] @288, probs[12] @320

// ---------------------------------------------------------------------------
// build: per-node banked linked lists (1 banked atomicExch + 1 coalesced
// write per edge). head pre-set to -1 by hipMemsetAsync(0xFF).
// Extra block (3125) computes the fused tiny matrices:
// (H0 stays zero in the reference => R-gate dead; only top 32 rows of Wl*
//  matter:  Az = Wz@Wlz[0:32,:],  cz = blz + bz@Wlz[0:32,:],  same for h.)
// ---------------------------------------------------------------------------
__global__ void build_pre_kernel(const int* __restrict__ ei, int* __restrict__ head,
                                 int* __restrict__ next,
                                 const float* __restrict__ Wz, const float* __restrict__ bz,
                                 const float* __restrict__ Wlz, const float* __restrict__ blz,
                                 const float* __restrict__ Wh, const float* __restrict__ bh,
                                 const float* __restrict__ Wlh, const float* __restrict__ blh,
                                 const float* __restrict__ attention,
                                 float* __restrict__ cst) {
    int tid = threadIdx.x;
    if (blockIdx.x < (NE / 256)) {          // 3125 blocks cover NE exactly
        int e = blockIdx.x * 256 + tid;
        int c = ei[NE + e];
        int old = atomicExch(&head[(e & (NBANK-1)) * NN + c], e);
        next[e] = old;
        return;
    }
    // one extra block: precompute cst
    if (tid < 128) {
        int f = tid >> 5, c = tid & 31;
        float s = 0.f, s2 = 0.f;
        #pragma unroll
        for (int k = 0; k < 32; ++k) {
            s  += Wz[f*32 + k] * Wlz[k*32 + c];
            s2 += Wh[f*32 + k] * Wlh[k*32 + c];
        }
        cst[tid]       = s;   // Az
        cst[160 + tid] = s2;  // Ah
    } else if (tid < 160) {
        int c = tid - 128;
        float s = blz[c], s2 = blh[c];
        #pragma unroll
        for (int k = 0; k < 32; ++k) {
            s  += bz[k] * Wlz[k*32 + c];
            s2 += bh[k] * Wlh[k*32 + c];
        }
        cst[128 + c] = s;   // cz
        cst[288 + c] = s2;  // ch
    } else if (tid == 160) {
        float m = -1e30f;
        for (int t = 0; t < TD; ++t) m = fmaxf(m, attention[t]);
        float e[TD], s = 0.f;
        #pragma unroll
        for (int t = 0; t < TD; ++t) { e[t] = __expf(attention[t] - m); s += e[t]; }
        float inv = 1.f / s;
        #pragma unroll
        for (int t = 0; t < TD; ++t) cst[320 + t] = e[t] * inv;
    }
}

// weighted in-degree: 8 lanes per node, one bank chain each (dep-depth ~2),
// then shfl-xor reduce within the 8-lane segment.
__global__ void degdis_kernel(const int* __restrict__ head, const int* __restrict__ next,
                              const float* __restrict__ w, float* __restrict__ dis) {
    int t = blockIdx.x * blockDim.x + threadIdx.x;   // NN*8 threads
    int i = t >> 3;
    int b = t & 7;
    if (i >= NN) return;
    float s = 0.f;
    int e = head[b * NN + i];
    while (e >= 0) { s += w[e]; e = next[e]; }
    s += __shfl_xor(s, 1, 8);
    s += __shfl_xor(s, 2, 8);
    s += __shfl_xor(s, 4, 8);
    if (b == 0) dis[i] = rsqrtf(s + 1.0f);
}

// ---------------------------------------------------------------------------
// Fused gather + GRU + output. 16 lanes/node, 16 nodes/block.
// Per round: lanes 0..7 stash up to 8 chain edges each in registers (static
// indices), shfl-scan counts, write a COMPACTED (row,norm) list to LDS, then
// lanes 0..11 run a uniform-trip unroll-4 gather over the list (4 independent
// 16B x-loads in flight per lane; LDS metadata reads broadcast).
// Phase B: GRU from LDS y. Phase C: output matvec.
// ---------------------------------------------------------------------------
__global__ __launch_bounds__(256) void gather_gru_kernel(
        const float4* __restrict__ x4, const float* __restrict__ dis,
        const int* __restrict__ head, const int* __restrict__ next,
        const int* __restrict__ ei, const float* __restrict__ w,
        const float* __restrict__ cst, const float* __restrict__ Wout,
        const float* __restrict__ bout, float* __restrict__ out) {
    __shared__ int2  smeta[16][64];      // compacted (row, norm) per node round
    __shared__ float sy[16][FT];
    __shared__ float hbuf[16][CD];
    __shared__ float sAz[128], sAh[128], sCz[32], sCh[32], sP[TD];
    __shared__ float sWout[CD * HD], sBout[HD];

    int tid = threadIdx.x;
    if (tid < 128) { sAz[tid] = cst[tid]; sAh[tid] = cst[160 + tid]; }
    if (tid < 32)  { sCz[tid] = cst[128 + tid]; sCh[tid] = cst[288 + tid]; }
    if (tid < TD)  { sP[tid] = cst[320 + tid]; sBout[tid] = bout[tid]; }
    for (int k = tid; k < CD * HD; k += 256) sWout[k] = Wout[k];
    __syncthreads();

    int g  = tid & 15;            // lane within node group
    int ln = tid >> 4;            // local node 0..15
    int i  = blockIdx.x * 16 + ln;

    float d = dis[i];
    float4 a = (g < 12) ? x4[i * (FT/4) + g] : make_float4(0.f,0.f,0.f,0.f);
    float4 acc = make_float4(0.f, 0.f, 0.f, 0.f);

    int e = (g < 8) ? head[g * NN + i] : -1;

    while (true) {
        // ---- stash up to 8 edges per bank-lane (static reg indices) ----
        int r0=0,r1=0,r2=0,r3=0,r4=0,r5=0,r6=0,r7=0;
        float n0=0,n1=0,n2=0,n3=0,n4=0,n5=0,n6=0,n7=0;
        int cnt = 0;
        #define STEP(RK,NK) if (e >= 0) { RK = ei[e]; NK = dis[RK] * w[e]; e = next[e]; ++cnt; }
        STEP(r0,n0) STEP(r1,n1) STEP(r2,n2) STEP(r3,n3)
        STEP(r4,n4) STEP(r5,n5) STEP(r6,n6) STEP(r7,n7)
        #undef STEP

        // ---- exclusive scan of cnt over the 16-lane segment ----
        int incl = cnt;
        #pragma unroll
        for (int dd = 1; dd < 8; dd <<= 1) {
            int t2 = __shfl_up(incl, dd, 16);
            if (g >= dd) incl += t2;
        }
        int S = __shfl(incl, 7, 16);      // total staged this round
        if (S == 0) break;
        int off = incl - cnt;

        // ---- compacted write ----
        if (cnt > 0) smeta[ln][off + 0] = make_int2(r0, __float_as_int(n0));
        if (cnt > 1) smeta[ln][off + 1] = make_int2(r1, __float_as_int(n1));
        if (cnt > 2) smeta[ln][off + 2] = make_int2(r2, __float_as_int(n2));
        if (cnt > 3) smeta[ln][off + 3] = make_int2(r3, __float_as_int(n3));
        if (cnt > 4) smeta[ln][off + 4] = make_int2(r4, __float_as_int(n4));
        if (cnt > 5) smeta[ln][off + 5] = make_int2(r5, __float_as_int(n5));
        if (cnt > 6) smeta[ln][off + 6] = make_int2(r6, __float_as_int(n6));
        if (cnt > 7) smeta[ln][off + 7] = make_int2(r7, __float_as_int(n7));
        __builtin_amdgcn_wave_barrier();   // same-wave LDS RAW: keep order

        // ---- uniform gather over compacted list ----
        if (g < 12) {
            #pragma unroll 4
            for (int k = 0; k < S; ++k) {
                int2 m = smeta[ln][k];
                float nv = __int_as_float(m.y);
                float4 v = x4[m.x * (FT/4) + g];
                acc.x += nv * v.x; acc.y += nv * v.y;
                acc.z += nv * v.z; acc.w += nv * v.w;
            }
        }
    }

    if (g < 12) {
        float s0 = d * d;
        sy[ln][g*4 + 0] = a.x * s0 + d * acc.x;
        sy[ln][g*4 + 1] = a.y * s0 + d * acc.y;
        sy[ln][g*4 + 2] = a.z * s0 + d * acc.z;
        sy[ln][g*4 + 3] = a.w * s0 + d * acc.w;
    }
    __syncthreads();

    // ---- Phase B: GRU, 2 channels per lane (c0=g, c1=g+16) ----
    {
        int c0 = g, c1 = g + 16;
        float az00 = sAz[c0], az01 = sAz[32+c0], az02 = sAz[64+c0], az03 = sAz[96+c0];
        float az10 = sAz[c1], az11 = sAz[32+c1], az12 = sAz[64+c1], az13 = sAz[96+c1];
        float ah00 = sAh[c0], ah01 = sAh[32+c0], ah02 = sAh[64+c0], ah03 = sAh[96+c0];
        float ah10 = sAh[c1], ah11 = sAh[32+c1], ah12 = sAh[64+c1], ah13 = sAh[96+c1];
        float cz0 = sCz[c0], cz1 = sCz[c1], ch0 = sCh[c0], ch1 = sCh[c1];

        float hacc0 = 0.f, hacc1 = 0.f;
        #pragma unroll
        for (int t = 0; t < TD; ++t) {
            float y0 = sy[ln][0*TD + t];
            float y1 = sy[ln][1*TD + t];
            float y2 = sy[ln][2*TD + t];
            float y3 = sy[ln][3*TD + t];
            float z0 = cz0 + y0*az00 + y1*az01 + y2*az02 + y3*az03;
            float z1 = cz1 + y0*az10 + y1*az11 + y2*az12 + y3*az13;
            float h0 = ch0 + y0*ah00 + y1*ah01 + y2*ah02 + y3*ah03;
            float h1 = ch1 + y0*ah10 + y1*ah11 + y2*ah12 + y3*ah13;
            float Z0 = 1.f / (1.f + __expf(-z0));
            float Z1 = 1.f / (1.f + __expf(-z1));
            float e0 = __expf(2.f * h0);
            float e1 = __expf(2.f * h1);
            float H0v = (e0 - 1.f) / (e0 + 1.f);
            float H1v = (e1 - 1.f) / (e1 + 1.f);
            float p = sP[t];
            hacc0 += p * (1.f - Z0) * H0v;
            hacc1 += p * (1.f - Z1) * H1v;
        }
        hbuf[ln][c0] = fmaxf(hacc0, 0.f);
        hbuf[ln][c1] = fmaxf(hacc1, 0.f);
    }
    __syncthreads();

    // ---- Phase C: out = relu(Hacc) @ Wout + bout ----
    if (tid < 16 * HD) {
        int lnode = tid / HD, hor = tid - lnode * HD;
        int gn = blockIdx.x * 16 + lnode;
        float s = sBout[hor];
        #pragma unroll
        for (int k = 0; k < CD; ++k) s += hbuf[lnode][k] * sWout[k * HD + hor];
        out[gn * HD + hor] = s;
    }
}

extern "C" void kernel_launch(void* const* d_in, const int* in_sizes, int n_in,
                              void* d_out, int out_size, void* d_ws, size_t ws_size,
                              hipStream_t stream) {
    const float* x      = (const float*)d_in[0];
    const int*   ei     = (const int*)d_in[1];    // int32, layout [rows..., cols...]
    const float* ew     = (const float*)d_in[2];
    const float* attn   = (const float*)d_in[3];
    const float* Wz     = (const float*)d_in[4];
    const float* bz     = (const float*)d_in[5];
    const float* Wlz    = (const float*)d_in[6];
    const float* blz    = (const float*)d_in[7];
    // d_in[8..11] = Wr, br, Wlr, blr — dead (H0 == 0 forever)
    const float* Wh     = (const float*)d_in[12];
    const float* bh     = (const float*)d_in[13];
    const float* Wlh    = (const float*)d_in[14];
    const float* blh    = (const float*)d_in[15];
    const float* Wout   = (const float*)d_in[16];
    const float* bout   = (const float*)d_in[17];
    float* out = (float*)d_out;

    float* ws   = (float*)d_ws;
    int*   head = (int*)(ws + OFF_HEAD);
    int*   next = (int*)(ws + OFF_NEXT);
    float* dis  = ws + OFF_DIS;
    float* cst  = ws + OFF_CST;

    // head = -1 via memset node (0xFF bytes); no init kernel
    hipMemsetAsync(head, 0xFF, NBANK * NN * sizeof(int), stream);

    build_pre_kernel<<<NE / 256 + 1, 256, 0, stream>>>(ei, head, next,
                                                       Wz, bz, Wlz, blz,
                                                       Wh, bh, Wlh, blh, attn, cst);

    degdis_kernel<<<(NN * 8 + 255) / 256, 256, 0, stream>>>(head, next, ew, dis);

    gather_gru_kernel<<<NN / 16, 256, 0, stream>>>(
        (const float4*)x, dis, head, next, ei, ew, cst, Wout, bout, out);
}

// Round 12
// 198.229 us; speedup vs baseline: 1.3340x; 1.0734x over previous
//
#include <hip/hip_runtime.h>
#include <hip/hip_bf16.h>

// Problem constants
#define NN 50000      // nodes
#define NE 800000     // edges
#define FD 4          // features
#define TD 12         // timesteps
#define CD 32         // channels
#define HD 12         // horizon
#define FT 48         // FD*TD
#define NBANK 8       // chain banks per node

// Workspace layout (4-byte element offsets)
#define OFF_HEAD   0                    // int[NBANK*NN]  chain heads
#define OFF_PAY    400000               // int4[NE] (row, w_bits, next, 0) 16B aligned
#define OFF_DIS    3600000              // float[NN]
#define OFF_CST    3650000              // float[512]
// cst block: Az[128] @0, cz[32] @128, Ah[128] @160, ch[32] @288, probs[12] @320

// ---------------------------------------------------------------------------
// build: per-node banked linked lists. One banked atomicExch + one coalesced
// 16B payload write per edge: pay4[e] = (row, w_bits, next, 0).
// head pre-set to -1 by hipMemsetAsync(0xFF).
// Extra block computes the fused tiny matrices:
// (H0 stays zero in the reference => R-gate dead; only top 32 rows of Wl*
//  matter:  Az = Wz@Wlz[0:32,:],  cz = blz + bz@Wlz[0:32,:],  same for h.)
// ---------------------------------------------------------------------------
__global__ void build_pre_kernel(const int* __restrict__ ei, const float* __restrict__ w,
                                 int* __restrict__ head, int4* __restrict__ pay4,
                                 const float* __restrict__ Wz, const float* __restrict__ bz,
                                 const float* __restrict__ Wlz, const float* __restrict__ blz,
                                 const float* __restrict__ Wh, const float* __restrict__ bh,
                                 const float* __restrict__ Wlh, const float* __restrict__ blh,
                                 const float* __restrict__ attention,
                                 float* __restrict__ cst) {
    int tid = threadIdx.x;
    if (blockIdx.x < (NE / 256)) {          // 3125 blocks cover NE exactly
        int e = blockIdx.x * 256 + tid;
        int r = ei[e];
        int c = ei[NE + e];
        int old = atomicExch(&head[(e & (NBANK-1)) * NN + c], e);
        pay4[e] = make_int4(r, __float_as_int(w[e]), old, 0);
        return;
    }
    // one extra block: precompute cst
    if (tid < 128) {
        int f = tid >> 5, c = tid & 31;
        float s = 0.f, s2 = 0.f;
        #pragma unroll
        for (int k = 0; k < 32; ++k) {
            s  += Wz[f*32 + k] * Wlz[k*32 + c];
            s2 += Wh[f*32 + k] * Wlh[k*32 + c];
        }
        cst[tid]       = s;   // Az
        cst[160 + tid] = s2;  // Ah
    } else if (tid < 160) {
        int c = tid - 128;
        float s = blz[c], s2 = blh[c];
        #pragma unroll
        for (int k = 0; k < 32; ++k) {
            s  += bz[k] * Wlz[k*32 + c];
            s2 += bh[k] * Wlh[k*32 + c];
        }
        cst[128 + c] = s;   // cz
        cst[288 + c] = s2;  // ch
    } else if (tid == 160) {
        float m = -1e30f;
        for (int t = 0; t < TD; ++t) m = fmaxf(m, attention[t]);
        float e[TD], s = 0.f;
        #pragma unroll
        for (int t = 0; t < TD; ++t) { e[t] = __expf(attention[t] - m); s += e[t]; }
        float inv = 1.f / s;
        #pragma unroll
        for (int t = 0; t < TD; ++t) cst[320 + t] = e[t] * inv;
    }
}

// weighted in-degree: 8 lanes per node, one bank chain each (dep-depth ~2),
// one random 16B payload read per hop, shfl-xor reduce over the 8-lane segment.
__global__ void degdis_kernel(const int* __restrict__ head, const int4* __restrict__ pay4,
                              float* __restrict__ dis) {
    int t = blockIdx.x * blockDim.x + threadIdx.x;   // NN*8 threads
    int i = t >> 3;
    int b = t & 7;
    if (i >= NN) return;
    float s = 0.f;
    int e = head[b * NN + i];
    while (e >= 0) {
        int4 p = pay4[e];
        s += __int_as_float(p.y);
        e = p.z;
    }
    s += __shfl_xor(s, 1, 8);
    s += __shfl_xor(s, 2, 8);
    s += __shfl_xor(s, 4, 8);
    if (b == 0) dis[i] = rsqrtf(s + 1.0f);
}

// ---------------------------------------------------------------------------
// Fused gather + GRU + output. 16 lanes/node, 16 nodes/block.
// Per round: lanes 0..7 stash up to 8 chain edges each in registers (static
// indices, one 16B pay4 read + one dis read per hop), shfl-scan counts, write
// a COMPACTED (row,norm) list to LDS, then ALL 16 lanes run a uniform-trip
// unroll-8 gather: lane g accumulates float3 chunk g (48 = 16 x float3, 192B
// fully coalesced per node group).
// Phase B: GRU from LDS y. Phase C: output matvec.
// ---------------------------------------------------------------------------
__global__ __launch_bounds__(256) void gather_gru_kernel(
        const float* __restrict__ x, const float* __restrict__ dis,
        const int* __restrict__ head, const int4* __restrict__ pay4,
        const float* __restrict__ cst, const float* __restrict__ Wout,
        const float* __restrict__ bout, float* __restrict__ out) {
    __shared__ int2  smeta[16][64];      // compacted (row, norm) per node round
    __shared__ float sy[16][FT];
    __shared__ float hbuf[16][CD];
    __shared__ float sAz[128], sAh[128], sCz[32], sCh[32], sP[TD];
    __shared__ float sWout[CD * HD], sBout[HD];

    int tid = threadIdx.x;
    if (tid < 128) { sAz[tid] = cst[tid]; sAh[tid] = cst[160 + tid]; }
    if (tid < 32)  { sCz[tid] = cst[128 + tid]; sCh[tid] = cst[288 + tid]; }
    if (tid < TD)  { sP[tid] = cst[320 + tid]; sBout[tid] = bout[tid]; }
    for (int k = tid; k < CD * HD; k += 256) sWout[k] = Wout[k];
    __syncthreads();

    int g  = tid & 15;            // lane within node group
    int ln = tid >> 4;            // local node 0..15
    int i  = blockIdx.x * 16 + ln;

    const float3* x3 = (const float3*)x;   // 16 float3 per row
    float d = dis[i];
    float3 a = x3[i * 16 + g];
    float ax = 0.f, ay = 0.f, az = 0.f;    // acc

    int e = (g < 8) ? head[g * NN + i] : -1;

    while (true) {
        // ---- stash up to 8 edges per bank-lane (static reg indices) ----
        int r0=0,r1=0,r2=0,r3=0,r4=0,r5=0,r6=0,r7=0;
        float n0=0,n1=0,n2=0,n3=0,n4=0,n5=0,n6=0,n7=0;
        int cnt = 0;
        #define STEP(RK,NK) if (e >= 0) { int4 p = pay4[e]; RK = p.x; \
            NK = dis[p.x] * __int_as_float(p.y); e = p.z; ++cnt; }
        STEP(r0,n0) STEP(r1,n1) STEP(r2,n2) STEP(r3,n3)
        STEP(r4,n4) STEP(r5,n5) STEP(r6,n6) STEP(r7,n7)
        #undef STEP

        // ---- exclusive scan of cnt over the 16-lane segment ----
        int incl = cnt;
        #pragma unroll
        for (int dd = 1; dd < 8; dd <<= 1) {
            int t2 = __shfl_up(incl, dd, 16);
            if (g >= dd) incl += t2;
        }
        int S = __shfl(incl, 7, 16);      // total staged this round
        if (S == 0) break;
        int off = incl - cnt;

        // ---- compacted write ----
        if (cnt > 0) smeta[ln][off + 0] = make_int2(r0, __float_as_int(n0));
        if (cnt > 1) smeta[ln][off + 1] = make_int2(r1, __float_as_int(n1));
        if (cnt > 2) smeta[ln][off + 2] = make_int2(r2, __float_as_int(n2));
        if (cnt > 3) smeta[ln][off + 3] = make_int2(r3, __float_as_int(n3));
        if (cnt > 4) smeta[ln][off + 4] = make_int2(r4, __float_as_int(n4));
        if (cnt > 5) smeta[ln][off + 5] = make_int2(r5, __float_as_int(n5));
        if (cnt > 6) smeta[ln][off + 6] = make_int2(r6, __float_as_int(n6));
        if (cnt > 7) smeta[ln][off + 7] = make_int2(r7, __float_as_int(n7));
        __builtin_amdgcn_wave_barrier();   // same-wave LDS RAW: keep order

        // ---- uniform gather over compacted list, all 16 lanes ----
        #pragma unroll 8
        for (int k = 0; k < S; ++k) {
            int2 m = smeta[ln][k];
            float nv = __int_as_float(m.y);
            float3 v = x3[m.x * 16 + g];
            ax += nv * v.x; ay += nv * v.y; az += nv * v.z;
        }
    }

    {
        float s0 = d * d;
        sy[ln][g*3 + 0] = a.x * s0 + d * ax;
        sy[ln][g*3 + 1] = a.y * s0 + d * ay;
        sy[ln][g*3 + 2] = a.z * s0 + d * az;
    }
    __syncthreads();

    // ---- Phase B: GRU, 2 channels per lane (c0=g, c1=g+16) ----
    {
        int c0 = g, c1 = g + 16;
        float az00 = sAz[c0], az01 = sAz[32+c0], az02 = sAz[64+c0], az03 = sAz[96+c0];
        float az10 = sAz[c1], az11 = sAz[32+c1], az12 = sAz[64+c1], az13 = sAz[96+c1];
        float ah00 = sAh[c0], ah01 = sAh[32+c0], ah02 = sAh[64+c0], ah03 = sAh[96+c0];
        float ah10 = sAh[c1], ah11 = sAh[32+c1], ah12 = sAh[64+c1], ah13 = sAh[96+c1];
        float cz0 = sCz[c0], cz1 = sCz[c1], ch0 = sCh[c0], ch1 = sCh[c1];

        float hacc0 = 0.f, hacc1 = 0.f;
        #pragma unroll
        for (int t = 0; t < TD; ++t) {
            float y0 = sy[ln][0*TD + t];
            float y1 = sy[ln][1*TD + t];
            float y2 = sy[ln][2*TD + t];
            float y3 = sy[ln][3*TD + t];
            float z0 = cz0 + y0*az00 + y1*az01 + y2*az02 + y3*az03;
            float z1 = cz1 + y0*az10 + y1*az11 + y2*az12 + y3*az13;
            float h0 = ch0 + y0*ah00 + y1*ah01 + y2*ah02 + y3*ah03;
            float h1 = ch1 + y0*ah10 + y1*ah11 + y2*ah12 + y3*ah13;
            float Z0 = 1.f / (1.f + __expf(-z0));
            float Z1 = 1.f / (1.f + __expf(-z1));
            float e0 = __expf(2.f * h0);
            float e1 = __expf(2.f * h1);
            float H0v = (e0 - 1.f) / (e0 + 1.f);
            float H1v = (e1 - 1.f) / (e1 + 1.f);
            float p = sP[t];
            hacc0 += p * (1.f - Z0) * H0v;
            hacc1 += p * (1.f - Z1) * H1v;
        }
        hbuf[ln][c0] = fmaxf(hacc0, 0.f);
        hbuf[ln][c1] = fmaxf(hacc1, 0.f);
    }
    __syncthreads();

    // ---- Phase C: out = relu(Hacc) @ Wout + bout ----
    if (tid < 16 * HD) {
        int lnode = tid / HD, hor = tid - lnode * HD;
        int gn = blockIdx.x * 16 + lnode;
        float s = sBout[hor];
        #pragma unroll
        for (int k = 0; k < CD; ++k) s += hbuf[lnode][k] * sWout[k * HD + hor];
        out[gn * HD + hor] = s;
    }
}

extern "C" void kernel_launch(void* const* d_in, const int* in_sizes, int n_in,
                              void* d_out, int out_size, void* d_ws, size_t ws_size,
                              hipStream_t stream) {
    const float* x      = (const float*)d_in[0];
    const int*   ei     = (const int*)d_in[1];    // int32, layout [rows..., cols...]
    const float* ew     = (const float*)d_in[2];
    const float* attn   = (const float*)d_in[3];
    const float* Wz     = (const float*)d_in[4];
    const float* bz     = (const float*)d_in[5];
    const float* Wlz    = (const float*)d_in[6];
    const float* blz    = (const float*)d_in[7];
    // d_in[8..11] = Wr, br, Wlr, blr — dead (H0 == 0 forever)
    const float* Wh     = (const float*)d_in[12];
    const float* bh     = (const float*)d_in[13];
    const float* Wlh    = (const float*)d_in[14];
    const float* blh    = (const float*)d_in[15];
    const float* Wout   = (const float*)d_in[16];
    const float* bout   = (const float*)d_in[17];
    float* out = (float*)d_out;

    float* ws   = (float*)d_ws;
    int*   head = (int*)(ws + OFF_HEAD);
    int4*  pay4 = (int4*)(ws + OFF_PAY);
    float* dis  = ws + OFF_DIS;
    float* cst  = ws + OFF_CST;

    // head = -1 via memset node (0xFF bytes); no init kernel
    hipMemsetAsync(head, 0xFF, NBANK * NN * sizeof(int), stream);

    build_pre_kernel<<<NE / 256 + 1, 256, 0, stream>>>(ei, ew, head, pay4,
                                                       Wz, bz, Wlz, blz,
                                                       Wh, bh, Wlh, blh, attn, cst);

    degdis_kernel<<<(NN * 8 + 255) / 256, 256, 0, stream>>>(head, pay4, dis);

    gather_gru_kernel<<<NN / 16, 256, 0, stream>>>(
        x, dis, head, pay4, cst, Wout, bout, out);
}